// Round 8
// baseline (446.123 us; speedup 1.0000x reference)
//
#include <hip/hip_runtime.h>
#include <math.h>

#define N_SAMP 8192
#define LAT 16
#define DID 8
#define DTR 8
#define KB 8
#define CTXD 256
#define HIDD 256
#define NRES 2
#define NBLK 8
#define PDIM 184
#define TAILF 3.0f
#define RB 32          // rows per WG; 1024 threads = 16 waves; 1 WG/CU

typedef unsigned short ushort_t;
typedef short short8v __attribute__((ext_vector_type(8)));
typedef float f32x4 __attribute__((ext_vector_type(4)));

// packed-weight sizes (elements)
#define WIN_PACK   73728   // 9 ksteps * 16 nblk * 512
#define WSQ_PACK   65536   // 8 * 16 * 512
#define WF_PACK    49152   // 8 * 12 * 512
#define BLK_PACK   516096  // WIN + 6*WSQ + WF
#define OFF_WSQ    9216    // in short8 units
#define OFF_WF     58368

__device__ __forceinline__ ushort_t f2bf(float f){
  unsigned u = __builtin_bit_cast(unsigned, f);
  unsigned r = (u + 0x7fffu + ((u>>16)&1u)) >> 16;
  return (ushort_t)r;
}
__device__ __forceinline__ float softplusf(float x){
  return (x > 20.0f) ? x : log1pf(expf(x));
}
__device__ __forceinline__ f32x4 MFMA(short8v a, short8v b, f32x4 c){
  return __builtin_amdgcn_mfma_f32_16x16x32_bf16(a, b, c, 0, 0, 0);
}

// ---- A-fragment-linear LDS tiles ----
// element (row,k) at idx16 = (k>>5)*128 + (row>>4)*64 + ((k>>3)&3)*16 + (row&15),
// byte = idx16*16 + (k&7)*2.  A-read (rfrag,kt): lane l reads idx16 = (kt*2+rfrag)*64+l
// -> consecutive lanes read consecutive 16B: conflict-free by construction.
__device__ __forceinline__ short8v ldAf(const ushort_t* tile, int rfrag, int kt, int lane){
  return *(const short8v*)(tile + (((kt*2 + rfrag)*64 + lane) << 3));
}
__device__ __forceinline__ void stA(ushort_t* tile, int row, int col, float v){
  int idx = ((((col>>5)*2 + (row>>4))*64) + (((col>>3)&3)<<4) + (row&15))*8 + (col&7);
  tile[idx] = f2bf(v);
}

// register-version inverse RQS (verified)
__device__ __forceinline__ void rqs_inv1(float x, const float* uw, const float* uh,
                                         const float* ud, float* outp, float* nladp)
{
  const float T = TAILF;
  bool inside = (x >= -T) && (x <= T);
  float cw[KB+1], wv[KB], ch[KB+1], hv[KB], dv[KB+1];
  {
    float m = uw[0];
    #pragma unroll
    for (int k=1;k<KB;k++) m = fmaxf(m, uw[k]);
    float e[KB]; float ssum = 0.f;
    #pragma unroll
    for (int k=0;k<KB;k++){ e[k] = expf(uw[k]-m); ssum += e[k]; }
    float inv = 1.f/ssum; float c = 0.f;
    cw[0] = -T;
    #pragma unroll
    for (int k=0;k<KB;k++){ c += 0.001f + (1.f-0.008f)*e[k]*inv; cw[k+1] = 2.f*T*c - T; }
    cw[KB] = T;
    #pragma unroll
    for (int k=0;k<KB;k++) wv[k] = cw[k+1]-cw[k];
  }
  {
    float m = uh[0];
    #pragma unroll
    for (int k=1;k<KB;k++) m = fmaxf(m, uh[k]);
    float e[KB]; float ssum = 0.f;
    #pragma unroll
    for (int k=0;k<KB;k++){ e[k] = expf(uh[k]-m); ssum += e[k]; }
    float inv = 1.f/ssum; float c = 0.f;
    ch[0] = -T;
    #pragma unroll
    for (int k=0;k<KB;k++){ c += 0.001f + (1.f-0.008f)*e[k]*inv; ch[k+1] = 2.f*T*c - T; }
    ch[KB] = T;
    #pragma unroll
    for (int k=0;k<KB;k++) hv[k] = ch[k+1]-ch[k];
  }
  dv[0] = 1.f; dv[KB] = 1.f;
  #pragma unroll
  for (int k=0;k<KB-1;k++) dv[k+1] = 0.001f + softplusf(ud[k]);

  float xc = fminf(fmaxf(x, -T), T);
  int idx = 0;
  #pragma unroll
  for (int k=1;k<KB;k++) idx += (xc >= ch[k]) ? 1 : 0;

  float icw=cw[0], iw=wv[0], ich=ch[0], ih=hv[0], d0=dv[0], d1=dv[1];
  #pragma unroll
  for (int k=1;k<KB;k++){
    bool sel = (idx==k);
    icw = sel?cw[k]:icw; iw = sel?wv[k]:iw; ich = sel?ch[k]:ich;
    ih = sel?hv[k]:ih; d0 = sel?dv[k]:d0; d1 = sel?dv[k+1]:d1;
  }
  float delta = ih/iw;
  float sq = d0 + d1 - 2.f*delta;
  float yv = xc - ich;
  float aa = yv*sq + ih*(delta-d0);
  float bb = ih*d0 - yv*sq;
  float cc = -delta*yv;
  float disc = fmaxf(bb*bb - 4.f*aa*cc, 0.f);
  float root = 2.f*cc / (-bb - sqrtf(disc));
  float o = root*iw + icw;
  float t1m = root*(1.f-root);
  float den = delta + sq*t1m;
  float num = delta*delta*(d1*root*root + 2.f*delta*t1m + d0*(1.f-root)*(1.f-root));
  float lad = logf(num) - 2.f*logf(den);
  *outp = inside ? o : x;
  *nladp = inside ? -lad : 0.f;
}

// LDS-knot apply (uncond spline)
__device__ __forceinline__ void rqs_apply_lds(float x, const float* cw, const float* ch,
                                              const float* dv, float* outp, float* nladp)
{
  const float T = TAILF;
  bool inside = (x >= -T) && (x <= T);
  float xc = fminf(fmaxf(x, -T), T);
  int idx = 0;
  #pragma unroll
  for (int k=1;k<KB;k++) idx += (xc >= ch[k]) ? 1 : 0;
  float icw = cw[idx], iw = cw[idx+1]-icw;
  float ich = ch[idx], ih = ch[idx+1]-ich;
  float d0 = dv[idx], d1 = dv[idx+1];
  float delta = ih/iw;
  float sq = d0 + d1 - 2.f*delta;
  float yv = xc - ich;
  float aa = yv*sq + ih*(delta-d0);
  float bb = ih*d0 - yv*sq;
  float cc = -delta*yv;
  float disc = fmaxf(bb*bb - 4.f*aa*cc, 0.f);
  float root = 2.f*cc / (-bb - sqrtf(disc));
  float o = root*iw + icw;
  float t1m = root*(1.f-root);
  float den = delta + sq*t1m;
  float num = delta*delta*(d1*root*root + 2.f*delta*t1m + d0*(1.f-root)*(1.f-root));
  float lad = logf(num) - 2.f*logf(den);
  *outp = inside ? o : x;
  *nladp = inside ? -lad : 0.f;
}

// pack all weights into B-fragment-linear bf16 layout (unchanged, verified)
__global__ __launch_bounds__(256) void pack_w_k(
  const float* __restrict__ W_in, const float* __restrict__ W1, const float* __restrict__ W2,
  const float* __restrict__ Wc, const float* __restrict__ Wf, ushort_t* __restrict__ wp)
{
  int t = blockIdx.x*256 + threadIdx.x;
  if (t >= 8*64512) return;
  int blk = t / 64512;
  int r = t % 64512;
  ushort_t* dst = wp + (size_t)blk*BLK_PACK;
  float vals[8];
  if (r < 9216){
    int kt = r/1024, n = (r/64)%16, lane = r%64;
    const float* w = W_in + (size_t)blk*264*256;
    int col = n*16 + (lane&15);
    #pragma unroll
    for (int j=0;j<8;j++){
      int k = kt*32 + (lane>>4)*8 + j;
      vals[j] = (k < 32) ? ((k < 8) ? w[k*256+col] : 0.f) : w[(k-24)*256+col];
    }
    dst += ((size_t)(kt*16+n)*64 + lane)*8;
  } else if ((r -= 9216) < 49152){
    int m = r/8192, rr = r%8192;
    int kt = rr/1024, n = (rr/64)%16, lane = rr%64;
    int j2 = m/3, which = m%3;
    const float* w = (which==0 ? W1 : which==1 ? W2 : Wc) + (size_t)(blk*2+j2)*256*256;
    int col = n*16 + (lane&15);
    #pragma unroll
    for (int j=0;j<8;j++){
      int k = kt*32 + (lane>>4)*8 + j;
      vals[j] = w[k*256+col];
    }
    dst += WIN_PACK + (size_t)m*WSQ_PACK + ((size_t)(kt*16+n)*64+lane)*8;
  } else {
    r -= 49152;
    int kt = r/768, n = (r/64)%12, lane = r%64;
    const float* w = Wf + (size_t)blk*256*184;
    int col = n*16 + (lane&15);
    #pragma unroll
    for (int j=0;j<8;j++){
      int k = kt*32 + (lane>>4)*8 + j;
      vals[j] = (col < 184) ? w[k*184+col] : 0.f;
    }
    dst += (size_t)OFF_WF*8 + ((size_t)(kt*12+n)*64+lane)*8;
  }
  #pragma unroll
  for (int j=0;j<8;j++) dst[j] = f2bf(vals[j]);
}

// ---- ONE fused kernel: init + all 8 flow blocks; 1024 thr, RB=32, 1 WG/CU ----
__global__ __launch_bounds__(1024,4) void flow_k(
  const float* __restrict__ x, const float* __restrict__ params,
  float* __restrict__ zg, float* __restrict__ logdet_g,
  const ushort_t* __restrict__ wpack,
  const float* __restrict__ b_in, const float* __restrict__ b1, const float* __restrict__ b2,
  const float* __restrict__ bc, const float* __restrict__ bf_,
  const float* __restrict__ un_w, const float* __restrict__ un_h, const float* __restrict__ un_d,
  const float* __restrict__ lu_lo, const float* __restrict__ lu_up,
  const float* __restrict__ lu_ud, const float* __restrict__ lu_b,
  const int* __restrict__ perms)
{
  __shared__ ushort_t s_ctb[8192];    // P0: ctx staging; afterwards: t-tile (16KB)
  __shared__ ushort_t s_hr[8192];     // relu(h)/h bf16, A-linear (16KB)
  __shared__ ushort_t s_azid[1024];   // G1 kt0 A tile (zid | zeros), A-linear (2KB)
  __shared__ float s_z[RB][16], s_y[RB][16];
  __shared__ float s_zid[RB][8], s_ztr[RB][8];
  __shared__ float s_pb[RB][193];     // spline params (pad 193)
  __shared__ float s_ld[RB];
  __shared__ float s_ucw[8][9], s_uch[8][9], s_ud8[8][9];
  __shared__ float s_lulo[120], s_luup[120], s_dg[16], s_slog[16], s_lub[16];
  __shared__ int   s_perm[16];

  const int tid = threadIdx.x;
  const int r0 = blockIdx.x * RB;
  const int wid = tid >> 6, lane = tid & 63;
  const int rA = lane & 15;

  auto stage_params = [&](int blk, int t2){
    if (t2 >= 0 && t2 < 120){
      s_lulo[t2] = lu_lo[blk*120 + t2];
      s_luup[t2] = lu_up[blk*120 + t2];
    } else if (t2 >= 128 && t2 < 144){
      int c = t2 - 128;
      s_perm[c] = perms[blk*16 + c];
      float dg = softplusf(lu_ud[blk*16 + c]) + 0.001f;
      s_dg[c] = dg; s_slog[c] = logf(dg);
      s_lub[c] = lu_b[blk*16 + c];
    } else if (t2 >= 192 && t2 < 200){
      int k8 = t2 - 192;
      const float* uwp = un_w + blk*64 + k8*8;
      const float* uhp = un_h + blk*64 + k8*8;
      const float* udp = un_d + blk*56 + k8*7;
      float m = uwp[0];
      #pragma unroll
      for (int k=1;k<8;k++) m = fmaxf(m, uwp[k]);
      float e[8], s = 0.f;
      #pragma unroll
      for (int k=0;k<8;k++){ e[k]=expf(uwp[k]-m); s+=e[k]; }
      float inv = 1.f/s, c = 0.f;
      s_ucw[k8][0] = -TAILF;
      #pragma unroll
      for (int k=0;k<8;k++){ c += 0.001f + (1.f-0.008f)*e[k]*inv; s_ucw[k8][k+1] = 2.f*TAILF*c - TAILF; }
      s_ucw[k8][8] = TAILF;
      m = uhp[0];
      #pragma unroll
      for (int k=1;k<8;k++) m = fmaxf(m, uhp[k]);
      s = 0.f;
      #pragma unroll
      for (int k=0;k<8;k++){ e[k]=expf(uhp[k]-m); s+=e[k]; }
      inv = 1.f/s; c = 0.f;
      s_uch[k8][0] = -TAILF;
      #pragma unroll
      for (int k=0;k<8;k++){ c += 0.001f + (1.f-0.008f)*e[k]*inv; s_uch[k8][k+1] = 2.f*TAILF*c - TAILF; }
      s_uch[k8][8] = TAILF;
      s_ud8[k8][0] = 1.f; s_ud8[k8][8] = 1.f;
      #pragma unroll
      for (int k=0;k<7;k++) s_ud8[k8][k+1] = 0.001f + softplusf(udp[k]);
    }
  };

  // ---- P0 (once): stage x, ctx(f32->bf16 A-linear into s_ctb), azid pad, logdet, blk7 params
  if (tid < 512){
    int row = tid >> 4, c = tid & 15;
    s_z[row][c] = x[(r0+row)*16 + c];
    const float* src = params + (size_t)(r0+row)*256 + c*16;
    float f[16];
    #pragma unroll
    for (int q=0;q<4;q++){
      float4 v = *(const float4*)(src + q*4);
      f[q*4]=v.x; f[q*4+1]=v.y; f[q*4+2]=v.z; f[q*4+3]=v.w;
    }
    short8v v0, v1;
    #pragma unroll
    for (int j=0;j<8;j++){ v0[j]=(short)f2bf(f[j]); v1[j]=(short)f2bf(f[8+j]); }
    int b = ((((c>>1)*2 + (row>>4))*64) + ((c&1)*2)*16 + (row&15))*8;
    *(short8v*)(s_ctb + b)       = v0;
    *(short8v*)(s_ctb + b + 128) = v1;
    if (tid < RB) s_ld[tid] = 0.f;
  } else {
    stage_params(NBLK-1, tid - 512);
  }
  // zero azid octs 1..3
  for (int i = tid; i < 96; i += 1024){
    int rf = i/48, rem = i%48, oct = 1 + rem/16, r = rem%16;
    short8v zv = (short8v){0,0,0,0,0,0,0,0};
    *(short8v*)(s_azid + ((rf*64 + oct*16 + r)<<3)) = zv;
  }
  __syncthreads();

  // ---- pin ctx A-fragments in registers for the whole kernel (64 VGPRs)
  short8v ctxA[2][8];
  #pragma unroll
  for (int kt=0; kt<8; ++kt){
    ctxA[0][kt] = ldAf(s_ctb, 0, kt, lane);
    ctxA[1][kt] = ldAf(s_ctb, 1, kt, lane);
  }
  // s_ctb is now free -> reused as the t-tile below.

  float hreg[2][4];

  for (int blk = NBLK-1; blk >= 0; --blk){
    __syncthreads();

    // ---- P1: U apply (permuted input)
    if (tid < 512){
      int row = tid >> 4, c = tid & 15;
      float zp[16];
      #pragma unroll
      for (int cc=0;cc<16;cc++) zp[cc] = s_z[row][s_perm[cc]];
      float acc = s_dg[c]*zp[c];
      #pragma unroll
      for (int cc=0;cc<16;cc++)
        if (cc > c) acc += s_luup[c*15 - (c*(c-1))/2 + (cc-c-1)] * zp[cc];
      s_y[row][c] = acc;
    }
    __syncthreads();

    // ---- P2: L apply + bias (overwrite s_z with w)
    if (tid < 512){
      int row = tid >> 4, c = tid & 15;
      float yp[16];
      #pragma unroll
      for (int cc=0;cc<16;cc++) yp[cc] = s_y[row][cc];
      float acc = yp[c] + s_lub[c];
      #pragma unroll
      for (int cc=0;cc<16;cc++)
        if (cc < c) acc += s_lulo[(c*(c-1))/2 + cc] * yp[cc];
      s_z[row][c] = acc;
    }
    __syncthreads();

    // ---- P4: uncond spline on even dims
    if (tid < 256){
      int row = tid >> 3, k = tid & 7;
      float o, nl;
      rqs_apply_lds(s_z[row][2*k], s_ucw[k], s_uch[k], s_ud8[k], &o, &nl);
      s_zid[row][k] = o;
      s_ztr[row][k] = s_z[row][2*k+1];
      s_azid[(((row>>4)*64) + (row&15))*8 + k] = f2bf(o);   // oct0, e=k
      float t = nl;
      t += __shfl_xor(t,1); t += __shfl_xor(t,2); t += __shfl_xor(t,4);
      if (k == 0){
        float sl = 0.f;
        #pragma unroll
        for (int c=0;c<16;c++) sl += s_slog[c];
        s_ld[row] += sl + t;
      }
    }
    __syncthreads();

    const short8v* Wpk8 = (const short8v*)(wpack + (size_t)blk*BLK_PACK);

    // ---- G1: h = [zid|ctx] @ W_in + b_in  (KT=9; A from regs; B depth-4 roll)
    {
      f32x4 acc[2];
      acc[0] = (f32x4){0,0,0,0}; acc[1] = (f32x4){0,0,0,0};
      const short8v* Wp = Wpk8;
      float bvv = b_in[blk*256 + wid*16 + rA];
      short8v az0 = *(const short8v*)(s_azid + (lane<<3));
      short8v az1 = *(const short8v*)(s_azid + ((64 + lane)<<3));
      short8v B[4];
      #pragma unroll
      for (int s=0;s<4;s++) B[s] = Wp[(size_t)(s*16 + wid)*64 + lane];
      #pragma unroll
      for (int kt=0; kt<9; ++kt){
        short8v b = B[kt&3];
        if (kt+4 < 9) B[kt&3] = Wp[(size_t)((kt+4)*16 + wid)*64 + lane];
        short8v a0 = (kt==0) ? az0 : ctxA[0][kt-1];
        short8v a1 = (kt==0) ? az1 : ctxA[1][kt-1];
        acc[0] = MFMA(a0, b, acc[0]);
        acc[1] = MFMA(a1, b, acc[1]);
      }
      int col = wid*16 + rA;
      #pragma unroll
      for (int f=0;f<2;f++)
        #pragma unroll
        for (int r=0;r<4;r++){
          int row = f*16 + (lane>>4)*4 + r;
          float h = acc[f][r] + bvv;
          hreg[f][r] = h;
          stA(s_hr, row, col, fmaxf(h, 0.f));
        }
    }
    __syncthreads();

    // ---- residual blocks
    #pragma unroll
    for (int j=0;j<NRES;j++){
      // S1: t = relu(relu(h) @ W1 + b1)   (A depth-2 from s_hr; B depth-4)
      {
        f32x4 acc[2];
        acc[0] = (f32x4){0,0,0,0}; acc[1] = (f32x4){0,0,0,0};
        const short8v* Wp = Wpk8 + OFF_WSQ + (size_t)(j*3+0)*8192;
        float bvv = b1[(blk*2+j)*256 + wid*16 + rA];
        short8v B[4], A0[2][2];
        #pragma unroll
        for (int s=0;s<4;s++) B[s] = Wp[(size_t)(s*16 + wid)*64 + lane];
        #pragma unroll
        for (int q=0;q<2;q++){ A0[0][q] = ldAf(s_hr, 0, q, lane); A0[1][q] = ldAf(s_hr, 1, q, lane); }
        #pragma unroll
        for (int kt=0; kt<8; ++kt){
          short8v b = B[kt&3];
          if (kt+4 < 8) B[kt&3] = Wp[(size_t)((kt+4)*16 + wid)*64 + lane];
          short8v a0 = A0[0][kt&1], a1 = A0[1][kt&1];
          if (kt+2 < 8){
            A0[0][kt&1] = ldAf(s_hr, 0, kt+2, lane);
            A0[1][kt&1] = ldAf(s_hr, 1, kt+2, lane);
          }
          acc[0] = MFMA(a0, b, acc[0]);
          acc[1] = MFMA(a1, b, acc[1]);
        }
        int col = wid*16 + rA;
        #pragma unroll
        for (int f=0;f<2;f++)
          #pragma unroll
          for (int r=0;r<4;r++){
            int row = f*16 + (lane>>4)*4 + r;
            stA(s_ctb, row, col, fmaxf(acc[f][r] + bvv, 0.f));
          }
      }
      __syncthreads();
      // S2: h += (t @ W2 + b2) * sigmoid(ctx @ Wc + bc)
      {
        f32x4 acc[2], accg[2];
        acc[0]=(f32x4){0,0,0,0}; acc[1]=(f32x4){0,0,0,0};
        accg[0]=(f32x4){0,0,0,0}; accg[1]=(f32x4){0,0,0,0};
        float b2v = b2[(blk*2+j)*256 + wid*16 + rA];
        float bcv = bc[(blk*2+j)*256 + wid*16 + rA];
        // gate: accg = ctx @ Wc   (A from regs; B depth-4)
        {
          const short8v* Wg = Wpk8 + OFF_WSQ + (size_t)(j*3+2)*8192;
          short8v B[4];
          #pragma unroll
          for (int s=0;s<4;s++) B[s] = Wg[(size_t)(s*16 + wid)*64 + lane];
          #pragma unroll
          for (int kt=0; kt<8; ++kt){
            short8v b = B[kt&3];
            if (kt+4 < 8) B[kt&3] = Wg[(size_t)((kt+4)*16 + wid)*64 + lane];
            accg[0] = MFMA(ctxA[0][kt], b, accg[0]);
            accg[1] = MFMA(ctxA[1][kt], b, accg[1]);
          }
        }
        // value: acc = t @ W2   (A depth-2 from s_ctb; B depth-4)
        {
          const short8v* Wv = Wpk8 + OFF_WSQ + (size_t)(j*3+1)*8192;
          short8v B[4], A0[2][2];
          #pragma unroll
          for (int s=0;s<4;s++) B[s] = Wv[(size_t)(s*16 + wid)*64 + lane];
          #pragma unroll
          for (int q=0;q<2;q++){ A0[0][q] = ldAf(s_ctb, 0, q, lane); A0[1][q] = ldAf(s_ctb, 1, q, lane); }
          #pragma unroll
          for (int kt=0; kt<8; ++kt){
            short8v b = B[kt&3];
            if (kt+4 < 8) B[kt&3] = Wv[(size_t)((kt+4)*16 + wid)*64 + lane];
            short8v a0 = A0[0][kt&1], a1 = A0[1][kt&1];
            if (kt+2 < 8){
              A0[0][kt&1] = ldAf(s_ctb, 0, kt+2, lane);
              A0[1][kt&1] = ldAf(s_ctb, 1, kt+2, lane);
            }
            acc[0] = MFMA(a0, b, acc[0]);
            acc[1] = MFMA(a1, b, acc[1]);
          }
        }
        bool last = (j == NRES-1);
        int col = wid*16 + rA;
        #pragma unroll
        for (int f=0;f<2;f++)
          #pragma unroll
          for (int r=0;r<4;r++){
            int row = f*16 + (lane>>4)*4 + r;
            float v = acc[f][r] + b2v;
            float g = accg[f][r] + bcv;
            float sg = 1.f/(1.f + expf(-g));
            float h = hreg[f][r] + v*sg;
            hreg[f][r] = h;
            stA(s_hr, row, col, last ? h : fmaxf(h, 0.f));  // G5 consumes PLAIN h
          }
      }
      __syncthreads();
    }

    // ---- G5: p = h @ Wf + bf  (12 col-blocks; waves 0-11; A depth-2; B depth-4)
    if (wid < 12){
      f32x4 acc[2];
      acc[0] = (f32x4){0,0,0,0}; acc[1] = (f32x4){0,0,0,0};
      const short8v* Wp = Wpk8 + OFF_WF;
      int col = wid*16 + rA;
      float bfv = (col < PDIM) ? bf_[blk*PDIM + col] : 0.f;
      short8v B[4], A0[2][2];
      #pragma unroll
      for (int s=0;s<4;s++) B[s] = Wp[(size_t)(s*12 + wid)*64 + lane];
      #pragma unroll
      for (int q=0;q<2;q++){ A0[0][q] = ldAf(s_hr, 0, q, lane); A0[1][q] = ldAf(s_hr, 1, q, lane); }
      #pragma unroll
      for (int kt=0; kt<8; ++kt){
        short8v b = B[kt&3];
        if (kt+4 < 8) B[kt&3] = Wp[(size_t)((kt+4)*12 + wid)*64 + lane];
        short8v a0 = A0[0][kt&1], a1 = A0[1][kt&1];
        if (kt+2 < 8){
          A0[0][kt&1] = ldAf(s_hr, 0, kt+2, lane);
          A0[1][kt&1] = ldAf(s_hr, 1, kt+2, lane);
        }
        acc[0] = MFMA(a0, b, acc[0]);
        acc[1] = MFMA(a1, b, acc[1]);
      }
      if (col < PDIM){
        #pragma unroll
        for (int f=0;f<2;f++)
          #pragma unroll
          for (int r=0;r<4;r++){
            int row = f*16 + (lane>>4)*4 + r;
            s_pb[row][col] = acc[f][r] + bfv;
          }
      }
    }
    __syncthreads();

    // ---- P8: conditional spline on odd dims + reinterleave; co-stage next blk
    if (tid < 256){
      int row = tid >> 3, k = tid & 7;
      float pr[23];
      #pragma unroll
      for (int jj=0;jj<23;jj++) pr[jj] = s_pb[row][k*23 + jj];
      float uw[8], uh[8], ud[7];
      #pragma unroll
      for (int b=0;b<8;b++){ uw[b] = pr[b]*0.0625f; uh[b] = pr[8+b]*0.0625f; }
      #pragma unroll
      for (int b=0;b<7;b++) ud[b] = pr[16+b];
      float o, nl;
      rqs_inv1(s_ztr[row][k], uw, uh, ud, &o, &nl);
      s_z[row][2*k]   = s_zid[row][k];
      s_z[row][2*k+1] = o;
      float t = nl;
      t += __shfl_xor(t,1); t += __shfl_xor(t,2); t += __shfl_xor(t,4);
      if (k == 0) s_ld[row] += t;
    } else if (blk > 0){
      stage_params(blk-1, tid - 512);
    }
  }
  __syncthreads();

  // ---- writeback
  if (tid < 512){
    int row = tid >> 4, c = tid & 15;
    zg[(r0+row)*16 + c] = s_z[row][c];
    if (tid < RB) logdet_g[r0+tid] = s_ld[tid];
  }
}

__global__ __launch_bounds__(64) void final_k(
  const float* __restrict__ ctx, const float* __restrict__ q0W,
  const float* __restrict__ q0b, const float* __restrict__ z,
  const float* __restrict__ logdet, float* __restrict__ out)
{
  int n = blockIdx.x*64 + threadIdx.x;
  if (n >= N_SAMP) return;
  float acc[2*LAT];
  #pragma unroll
  for (int m=0;m<2*LAT;m++) acc[m] = q0b[m];
  for (int k=0;k<CTXD;k+=4){
    float4 cv = *(const float4*)&ctx[n*CTXD + k];
    #pragma unroll
    for (int m=0;m<2*LAT;m++){
      acc[m] = fmaf(cv.x, q0W[(k+0)*2*LAT + m], acc[m]);
      acc[m] = fmaf(cv.y, q0W[(k+1)*2*LAT + m], acc[m]);
      acc[m] = fmaf(cv.z, q0W[(k+2)*2*LAT + m], acc[m]);
      acc[m] = fmaf(cv.w, q0W[(k+3)*2*LAT + m], acc[m]);
    }
  }
  float s = 0.f;
  #pragma unroll
  for (int dd=0;dd<LAT;dd++){
    float ls = acc[LAT+dd];
    float t = (z[n*LAT+dd] - acc[dd]) * expf(-ls);
    s += ls + 0.5f*t*t;
  }
  float logp = -14.703016531f - s;
  out[n] = -(logp + logdet[n]);
}

extern "C" void kernel_launch(void* const* d_in, const int* in_sizes, int n_in,
                              void* d_out, int out_size, void* d_ws, size_t ws_size,
                              hipStream_t stream)
{
  const float* x      = (const float*)d_in[0];
  const float* params = (const float*)d_in[1];
  const float* W_in   = (const float*)d_in[2];
  const float* b_in   = (const float*)d_in[3];
  const float* W1     = (const float*)d_in[4];
  const float* b1     = (const float*)d_in[5];
  const float* W2     = (const float*)d_in[6];
  const float* b2     = (const float*)d_in[7];
  const float* Wc     = (const float*)d_in[8];
  const float* bc     = (const float*)d_in[9];
  const float* Wf     = (const float*)d_in[10];
  const float* bf_    = (const float*)d_in[11];
  const float* un_w   = (const float*)d_in[12];
  const float* un_h   = (const float*)d_in[13];
  const float* un_d   = (const float*)d_in[14];
  const float* lu_lo  = (const float*)d_in[15];
  const float* lu_up  = (const float*)d_in[16];
  const float* lu_ud  = (const float*)d_in[17];
  const float* lu_b   = (const float*)d_in[18];
  const float* q0W    = (const float*)d_in[19];
  const float* q0b    = (const float*)d_in[20];
  const int*   perms  = (const int*)d_in[21];
  float* out = (float*)d_out;

  float* ws      = (float*)d_ws;
  float* z       = ws;                           // 131072 f
  float* logdet  = z + N_SAMP*LAT;               // 8192 f
  ushort_t* wpk  = (ushort_t*)(logdet + N_SAMP); // 4128768 us

  pack_w_k<<<dim3(2016), 256, 0, stream>>>(W_in, W1, W2, Wc, Wf, wpk);
  flow_k<<<dim3(N_SAMP/RB), 1024, 0, stream>>>(
      x, params, z, logdet, wpk,
      b_in, b1, b2, bc, bf_,
      un_w, un_h, un_d, lu_lo, lu_up, lu_ud, lu_b, perms);
  final_k<<<dim3(N_SAMP/64), 64, 0, stream>>>(params, q0W, q0b, z, logdet, out);
}

// Round 9
// 343.672 us; speedup vs baseline: 1.2981x; 1.2981x over previous
//
#include <hip/hip_runtime.h>
#include <math.h>

#define N_SAMP 8192
#define LAT 16
#define DID 8
#define DTR 8
#define KB 8
#define CTXD 256
#define HIDD 256
#define NRES 2
#define NBLK 8
#define PDIM 184
#define TAILF 3.0f
#define RB 32          // rows per WG; 1024 threads = 16 waves; 1 WG/CU

typedef unsigned short ushort_t;
typedef short short8v __attribute__((ext_vector_type(8)));
typedef float f32x4 __attribute__((ext_vector_type(4)));

// packed-weight sizes (elements)
#define WIN_PACK   73728   // 9 ksteps * 16 nblk * 512
#define WSQ_PACK   65536   // 8 * 16 * 512
#define WF_PACK    49152   // 8 * 12 * 512
#define BLK_PACK   516096  // WIN + 6*WSQ + WF
#define OFF_WSQ    9216    // in short8 units
#define OFF_WF     58368

__device__ __forceinline__ ushort_t f2bf(float f){
  unsigned u = __builtin_bit_cast(unsigned, f);
  unsigned r = (u + 0x7fffu + ((u>>16)&1u)) >> 16;
  return (ushort_t)r;
}
__device__ __forceinline__ float softplusf(float x){
  return (x > 20.0f) ? x : log1pf(expf(x));
}
__device__ __forceinline__ f32x4 MFMA(short8v a, short8v b, f32x4 c){
  return __builtin_amdgcn_mfma_f32_16x16x32_bf16(a, b, c, 0, 0, 0);
}

// ---- A-fragment-linear LDS tiles ----
// element (row,k) at idx16 = (k>>5)*128 + (row>>4)*64 + ((k>>3)&3)*16 + (row&15),
// byte = idx16*16 + (k&7)*2.  A-read (rfrag,kt): lane l reads idx16 = (kt*2+rfrag)*64+l
// -> consecutive lanes read consecutive 16B: conflict-free by construction.
__device__ __forceinline__ short8v ldAf(const ushort_t* tile, int rfrag, int kt, int lane){
  return *(const short8v*)(tile + (((kt*2 + rfrag)*64 + lane) << 3));
}
__device__ __forceinline__ void stA(ushort_t* tile, int row, int col, float v){
  int idx = ((((col>>5)*2 + (row>>4))*64) + (((col>>3)&3)<<4) + (row&15))*8 + (col&7);
  tile[idx] = f2bf(v);
}

// register-version inverse RQS (verified)
__device__ __forceinline__ void rqs_inv1(float x, const float* uw, const float* uh,
                                         const float* ud, float* outp, float* nladp)
{
  const float T = TAILF;
  bool inside = (x >= -T) && (x <= T);
  float cw[KB+1], wv[KB], ch[KB+1], hv[KB], dv[KB+1];
  {
    float m = uw[0];
    #pragma unroll
    for (int k=1;k<KB;k++) m = fmaxf(m, uw[k]);
    float e[KB]; float ssum = 0.f;
    #pragma unroll
    for (int k=0;k<KB;k++){ e[k] = expf(uw[k]-m); ssum += e[k]; }
    float inv = 1.f/ssum; float c = 0.f;
    cw[0] = -T;
    #pragma unroll
    for (int k=0;k<KB;k++){ c += 0.001f + (1.f-0.008f)*e[k]*inv; cw[k+1] = 2.f*T*c - T; }
    cw[KB] = T;
    #pragma unroll
    for (int k=0;k<KB;k++) wv[k] = cw[k+1]-cw[k];
  }
  {
    float m = uh[0];
    #pragma unroll
    for (int k=1;k<KB;k++) m = fmaxf(m, uh[k]);
    float e[KB]; float ssum = 0.f;
    #pragma unroll
    for (int k=0;k<KB;k++){ e[k] = expf(uh[k]-m); ssum += e[k]; }
    float inv = 1.f/ssum; float c = 0.f;
    ch[0] = -T;
    #pragma unroll
    for (int k=0;k<KB;k++){ c += 0.001f + (1.f-0.008f)*e[k]*inv; ch[k+1] = 2.f*T*c - T; }
    ch[KB] = T;
    #pragma unroll
    for (int k=0;k<KB;k++) hv[k] = ch[k+1]-ch[k];
  }
  dv[0] = 1.f; dv[KB] = 1.f;
  #pragma unroll
  for (int k=0;k<KB-1;k++) dv[k+1] = 0.001f + softplusf(ud[k]);

  float xc = fminf(fmaxf(x, -T), T);
  int idx = 0;
  #pragma unroll
  for (int k=1;k<KB;k++) idx += (xc >= ch[k]) ? 1 : 0;

  float icw=cw[0], iw=wv[0], ich=ch[0], ih=hv[0], d0=dv[0], d1=dv[1];
  #pragma unroll
  for (int k=1;k<KB;k++){
    bool sel = (idx==k);
    icw = sel?cw[k]:icw; iw = sel?wv[k]:iw; ich = sel?ch[k]:ich;
    ih = sel?hv[k]:ih; d0 = sel?dv[k]:d0; d1 = sel?dv[k+1]:d1;
  }
  float delta = ih/iw;
  float sq = d0 + d1 - 2.f*delta;
  float yv = xc - ich;
  float aa = yv*sq + ih*(delta-d0);
  float bb = ih*d0 - yv*sq;
  float cc = -delta*yv;
  float disc = fmaxf(bb*bb - 4.f*aa*cc, 0.f);
  float root = 2.f*cc / (-bb - sqrtf(disc));
  float o = root*iw + icw;
  float t1m = root*(1.f-root);
  float den = delta + sq*t1m;
  float num = delta*delta*(d1*root*root + 2.f*delta*t1m + d0*(1.f-root)*(1.f-root));
  float lad = logf(num) - 2.f*logf(den);
  *outp = inside ? o : x;
  *nladp = inside ? -lad : 0.f;
}

// LDS-knot apply (uncond spline)
__device__ __forceinline__ void rqs_apply_lds(float x, const float* cw, const float* ch,
                                              const float* dv, float* outp, float* nladp)
{
  const float T = TAILF;
  bool inside = (x >= -T) && (x <= T);
  float xc = fminf(fmaxf(x, -T), T);
  int idx = 0;
  #pragma unroll
  for (int k=1;k<KB;k++) idx += (xc >= ch[k]) ? 1 : 0;
  float icw = cw[idx], iw = cw[idx+1]-icw;
  float ich = ch[idx], ih = ch[idx+1]-ich;
  float d0 = dv[idx], d1 = dv[idx+1];
  float delta = ih/iw;
  float sq = d0 + d1 - 2.f*delta;
  float yv = xc - ich;
  float aa = yv*sq + ih*(delta-d0);
  float bb = ih*d0 - yv*sq;
  float cc = -delta*yv;
  float disc = fmaxf(bb*bb - 4.f*aa*cc, 0.f);
  float root = 2.f*cc / (-bb - sqrtf(disc));
  float o = root*iw + icw;
  float t1m = root*(1.f-root);
  float den = delta + sq*t1m;
  float num = delta*delta*(d1*root*root + 2.f*delta*t1m + d0*(1.f-root)*(1.f-root));
  float lad = logf(num) - 2.f*logf(den);
  *outp = inside ? o : x;
  *nladp = inside ? -lad : 0.f;
}

// pack all weights into B-fragment-linear bf16 layout (unchanged, verified)
__global__ __launch_bounds__(256) void pack_w_k(
  const float* __restrict__ W_in, const float* __restrict__ W1, const float* __restrict__ W2,
  const float* __restrict__ Wc, const float* __restrict__ Wf, ushort_t* __restrict__ wp)
{
  int t = blockIdx.x*256 + threadIdx.x;
  if (t >= 8*64512) return;
  int blk = t / 64512;
  int r = t % 64512;
  ushort_t* dst = wp + (size_t)blk*BLK_PACK;
  float vals[8];
  if (r < 9216){
    int kt = r/1024, n = (r/64)%16, lane = r%64;
    const float* w = W_in + (size_t)blk*264*256;
    int col = n*16 + (lane&15);
    #pragma unroll
    for (int j=0;j<8;j++){
      int k = kt*32 + (lane>>4)*8 + j;
      vals[j] = (k < 32) ? ((k < 8) ? w[k*256+col] : 0.f) : w[(k-24)*256+col];
    }
    dst += ((size_t)(kt*16+n)*64 + lane)*8;
  } else if ((r -= 9216) < 49152){
    int m = r/8192, rr = r%8192;
    int kt = rr/1024, n = (rr/64)%16, lane = rr%64;
    int j2 = m/3, which = m%3;
    const float* w = (which==0 ? W1 : which==1 ? W2 : Wc) + (size_t)(blk*2+j2)*256*256;
    int col = n*16 + (lane&15);
    #pragma unroll
    for (int j=0;j<8;j++){
      int k = kt*32 + (lane>>4)*8 + j;
      vals[j] = w[k*256+col];
    }
    dst += WIN_PACK + (size_t)m*WSQ_PACK + ((size_t)(kt*16+n)*64+lane)*8;
  } else {
    r -= 49152;
    int kt = r/768, n = (r/64)%12, lane = r%64;
    const float* w = Wf + (size_t)blk*256*184;
    int col = n*16 + (lane&15);
    #pragma unroll
    for (int j=0;j<8;j++){
      int k = kt*32 + (lane>>4)*8 + j;
      vals[j] = (col < 184) ? w[k*184+col] : 0.f;
    }
    dst += (size_t)OFF_WF*8 + ((size_t)(kt*12+n)*64+lane)*8;
  }
  #pragma unroll
  for (int j=0;j<8;j++) dst[j] = f2bf(vals[j]);
}

// ---- ONE fused kernel: init + all 8 flow blocks; 1024 thr, RB=32, 1 WG/CU ----
// Wave mapping: f = wid>>3 (row-fragment), cb = wid&7, n0 = 2*cb (2 col-blocks/wave).
__global__ __launch_bounds__(1024,4) void flow_k(
  const float* __restrict__ x, const float* __restrict__ params,
  float* __restrict__ zg, float* __restrict__ logdet_g,
  const ushort_t* __restrict__ wpack,
  const float* __restrict__ b_in, const float* __restrict__ b1, const float* __restrict__ b2,
  const float* __restrict__ bc, const float* __restrict__ bf_,
  const float* __restrict__ un_w, const float* __restrict__ un_h, const float* __restrict__ un_d,
  const float* __restrict__ lu_lo, const float* __restrict__ lu_up,
  const float* __restrict__ lu_ud, const float* __restrict__ lu_b,
  const int* __restrict__ perms)
{
  __shared__ ushort_t s_actx[8192];   // ctx bf16, A-linear, resident all 8 blocks (16KB)
  __shared__ ushort_t s_hr[8192];     // relu(h)/h bf16, A-linear (16KB)
  __shared__ ushort_t s_tb[8192];     // relu(t1) bf16, A-linear (16KB)
  __shared__ ushort_t s_azid[1024];   // G1 kt0 A tile (zid | zeros), A-linear (2KB)
  __shared__ float s_z[RB][16], s_y[RB][16];
  __shared__ float s_zid[RB][8], s_ztr[RB][8];
  __shared__ float s_pb[RB][193];     // spline params (pad 193)
  __shared__ float s_ld[RB];
  __shared__ float s_ucw[8][9], s_uch[8][9], s_ud8[8][9];
  __shared__ float s_lulo[120], s_luup[120], s_dg[16], s_slog[16], s_lub[16];
  __shared__ int   s_perm[16];

  const int tid = threadIdx.x;
  const int r0 = blockIdx.x * RB;
  const int wid = tid >> 6, lane = tid & 63;
  const int rA = lane & 15;
  const int f  = wid >> 3;          // row fragment (0: rows 0-15, 1: rows 16-31)
  const int cb = wid & 7;
  const int n0 = 2*cb;

  auto stage_params = [&](int blk, int t2){
    if (t2 >= 0 && t2 < 120){
      s_lulo[t2] = lu_lo[blk*120 + t2];
      s_luup[t2] = lu_up[blk*120 + t2];
    } else if (t2 >= 128 && t2 < 144){
      int c = t2 - 128;
      s_perm[c] = perms[blk*16 + c];
      float dg = softplusf(lu_ud[blk*16 + c]) + 0.001f;
      s_dg[c] = dg; s_slog[c] = logf(dg);
      s_lub[c] = lu_b[blk*16 + c];
    } else if (t2 >= 192 && t2 < 200){
      int k8 = t2 - 192;
      const float* uwp = un_w + blk*64 + k8*8;
      const float* uhp = un_h + blk*64 + k8*8;
      const float* udp = un_d + blk*56 + k8*7;
      float m = uwp[0];
      #pragma unroll
      for (int k=1;k<8;k++) m = fmaxf(m, uwp[k]);
      float e[8], s = 0.f;
      #pragma unroll
      for (int k=0;k<8;k++){ e[k]=expf(uwp[k]-m); s+=e[k]; }
      float inv = 1.f/s, c = 0.f;
      s_ucw[k8][0] = -TAILF;
      #pragma unroll
      for (int k=0;k<8;k++){ c += 0.001f + (1.f-0.008f)*e[k]*inv; s_ucw[k8][k+1] = 2.f*TAILF*c - TAILF; }
      s_ucw[k8][8] = TAILF;
      m = uhp[0];
      #pragma unroll
      for (int k=1;k<8;k++) m = fmaxf(m, uhp[k]);
      s = 0.f;
      #pragma unroll
      for (int k=0;k<8;k++){ e[k]=expf(uhp[k]-m); s+=e[k]; }
      inv = 1.f/s; c = 0.f;
      s_uch[k8][0] = -TAILF;
      #pragma unroll
      for (int k=0;k<8;k++){ c += 0.001f + (1.f-0.008f)*e[k]*inv; s_uch[k8][k+1] = 2.f*TAILF*c - TAILF; }
      s_uch[k8][8] = TAILF;
      s_ud8[k8][0] = 1.f; s_ud8[k8][8] = 1.f;
      #pragma unroll
      for (int k=0;k<7;k++) s_ud8[k8][k+1] = 0.001f + softplusf(udp[k]);
    }
  };

  // ---- P0 (once): stage x, ctx(f32->bf16 A-linear), azid pad, logdet, blk7 params
  if (tid < 512){
    int row = tid >> 4, c = tid & 15;
    s_z[row][c] = x[(r0+row)*16 + c];
    const float* src = params + (size_t)(r0+row)*256 + c*16;
    float fv[16];
    #pragma unroll
    for (int q=0;q<4;q++){
      float4 v = *(const float4*)(src + q*4);
      fv[q*4]=v.x; fv[q*4+1]=v.y; fv[q*4+2]=v.z; fv[q*4+3]=v.w;
    }
    short8v v0, v1;
    #pragma unroll
    for (int j=0;j<8;j++){ v0[j]=(short)f2bf(fv[j]); v1[j]=(short)f2bf(fv[8+j]); }
    int b = ((((c>>1)*2 + (row>>4))*64) + ((c&1)*2)*16 + (row&15))*8;
    *(short8v*)(s_actx + b)       = v0;
    *(short8v*)(s_actx + b + 128) = v1;
    if (tid < RB) s_ld[tid] = 0.f;
  } else {
    stage_params(NBLK-1, tid - 512);
  }
  // zero azid octs 1..3
  for (int i = tid; i < 96; i += 1024){
    int rf = i/48, rem = i%48, oct = 1 + rem/16, r = rem%16;
    short8v zv = (short8v){0,0,0,0,0,0,0,0};
    *(short8v*)(s_azid + ((rf*64 + oct*16 + r)<<3)) = zv;
  }

  float hreg[2][4];   // [col-block][reg] for this wave's row fragment

  for (int blk = NBLK-1; blk >= 0; --blk){
    __syncthreads();

    // ---- P1: U apply (permuted input)
    if (tid < 512){
      int row = tid >> 4, c = tid & 15;
      float zp[16];
      #pragma unroll
      for (int cc=0;cc<16;cc++) zp[cc] = s_z[row][s_perm[cc]];
      float acc = s_dg[c]*zp[c];
      #pragma unroll
      for (int cc=0;cc<16;cc++)
        if (cc > c) acc += s_luup[c*15 - (c*(c-1))/2 + (cc-c-1)] * zp[cc];
      s_y[row][c] = acc;
    }
    __syncthreads();

    // ---- P2: L apply + bias (overwrite s_z with w)
    if (tid < 512){
      int row = tid >> 4, c = tid & 15;
      float yp[16];
      #pragma unroll
      for (int cc=0;cc<16;cc++) yp[cc] = s_y[row][cc];
      float acc = yp[c] + s_lub[c];
      #pragma unroll
      for (int cc=0;cc<16;cc++)
        if (cc < c) acc += s_lulo[(c*(c-1))/2 + cc] * yp[cc];
      s_z[row][c] = acc;
    }
    __syncthreads();

    // ---- P4: uncond spline on even dims
    if (tid < 256){
      int row = tid >> 3, k = tid & 7;
      float o, nl;
      rqs_apply_lds(s_z[row][2*k], s_ucw[k], s_uch[k], s_ud8[k], &o, &nl);
      s_zid[row][k] = o;
      s_ztr[row][k] = s_z[row][2*k+1];
      s_azid[(((row>>4)*64) + (row&15))*8 + k] = f2bf(o);   // oct0, e=k
      float t = nl;
      t += __shfl_xor(t,1); t += __shfl_xor(t,2); t += __shfl_xor(t,4);
      if (k == 0){
        float sl = 0.f;
        #pragma unroll
        for (int c=0;c<16;c++) sl += s_slog[c];
        s_ld[row] += sl + t;
      }
    }
    __syncthreads();

    const short8v* Wpk8 = (const short8v*)(wpack + (size_t)blk*BLK_PACK);

    // ---- G1: h = [zid|ctx] @ W_in + b_in  (KT=9; 1 rfrag x 2 col-blocks)
    {
      f32x4 acc[2];
      acc[0] = (f32x4){0,0,0,0}; acc[1] = (f32x4){0,0,0,0};
      const short8v* Wp = Wpk8;
      float bvv[2] = { b_in[blk*256 + n0*16 + rA], b_in[blk*256 + (n0+1)*16 + rA] };
      short8v B[2][2], A[2];
      B[0][0] = Wp[(size_t)(0*16 + n0  )*64 + lane];
      B[0][1] = Wp[(size_t)(0*16 + n0+1)*64 + lane];
      B[1][0] = Wp[(size_t)(1*16 + n0  )*64 + lane];
      B[1][1] = Wp[(size_t)(1*16 + n0+1)*64 + lane];
      A[0] = *(const short8v*)(s_azid + ((f*64 + lane)<<3));
      #pragma unroll
      for (int kt=0; kt<9; ++kt){
        short8v b0 = B[kt&1][0], b1 = B[kt&1][1];
        if (kt+2 < 9){
          B[kt&1][0] = Wp[(size_t)((kt+2)*16 + n0  )*64 + lane];
          B[kt&1][1] = Wp[(size_t)((kt+2)*16 + n0+1)*64 + lane];
        }
        short8v a = A[kt&1];
        if (kt+1 < 9) A[(kt+1)&1] = ldAf(s_actx, f, kt, lane);  // ctx kt feeds step kt+1
        acc[0] = MFMA(a, b0, acc[0]);
        acc[1] = MFMA(a, b1, acc[1]);
      }
      #pragma unroll
      for (int ni=0;ni<2;ni++){
        int col = (n0+ni)*16 + rA;
        #pragma unroll
        for (int r=0;r<4;r++){
          int row = f*16 + (lane>>4)*4 + r;
          float h = acc[ni][r] + bvv[ni];
          hreg[ni][r] = h;
          stA(s_hr, row, col, fmaxf(h, 0.f));
        }
      }
    }
    __syncthreads();

    // ---- residual blocks
    #pragma unroll
    for (int j=0;j<NRES;j++){
      f32x4 accg[2];
      accg[0]=(f32x4){0,0,0,0}; accg[1]=(f32x4){0,0,0,0};
      // S1: t = relu(relu(h) @ W1 + b1)
      {
        f32x4 acc[2];
        acc[0] = (f32x4){0,0,0,0}; acc[1] = (f32x4){0,0,0,0};
        const short8v* Wp = Wpk8 + OFF_WSQ + (size_t)(j*3+0)*8192;
        float bvv[2] = { b1[(blk*2+j)*256 + n0*16 + rA], b1[(blk*2+j)*256 + (n0+1)*16 + rA] };
        short8v B[2][2], A[2];
        B[0][0] = Wp[(size_t)(0*16 + n0  )*64 + lane];
        B[0][1] = Wp[(size_t)(0*16 + n0+1)*64 + lane];
        B[1][0] = Wp[(size_t)(1*16 + n0  )*64 + lane];
        B[1][1] = Wp[(size_t)(1*16 + n0+1)*64 + lane];
        A[0] = ldAf(s_hr, f, 0, lane);
        #pragma unroll
        for (int kt=0; kt<8; ++kt){
          short8v b0 = B[kt&1][0], b1f = B[kt&1][1];
          if (kt+2 < 8){
            B[kt&1][0] = Wp[(size_t)((kt+2)*16 + n0  )*64 + lane];
            B[kt&1][1] = Wp[(size_t)((kt+2)*16 + n0+1)*64 + lane];
          }
          short8v a = A[kt&1];
          if (kt+1 < 8) A[(kt+1)&1] = ldAf(s_hr, f, kt+1, lane);
          acc[0] = MFMA(a, b0, acc[0]);
          acc[1] = MFMA(a, b1f, acc[1]);
        }
        #pragma unroll
        for (int ni=0;ni<2;ni++){
          int col = (n0+ni)*16 + rA;
          #pragma unroll
          for (int r=0;r<4;r++){
            int row = f*16 + (lane>>4)*4 + r;
            stA(s_tb, row, col, fmaxf(acc[ni][r] + bvv[ni], 0.f));
          }
        }
      }
      // gate GEMM: accg = ctx @ Wc — independent of t, runs BEFORE the barrier
      {
        const short8v* Wg = Wpk8 + OFF_WSQ + (size_t)(j*3+2)*8192;
        short8v B[2][2], A[2];
        B[0][0] = Wg[(size_t)(0*16 + n0  )*64 + lane];
        B[0][1] = Wg[(size_t)(0*16 + n0+1)*64 + lane];
        B[1][0] = Wg[(size_t)(1*16 + n0  )*64 + lane];
        B[1][1] = Wg[(size_t)(1*16 + n0+1)*64 + lane];
        A[0] = ldAf(s_actx, f, 0, lane);
        #pragma unroll
        for (int kt=0; kt<8; ++kt){
          short8v b0 = B[kt&1][0], b1f = B[kt&1][1];
          if (kt+2 < 8){
            B[kt&1][0] = Wg[(size_t)((kt+2)*16 + n0  )*64 + lane];
            B[kt&1][1] = Wg[(size_t)((kt+2)*16 + n0+1)*64 + lane];
          }
          short8v a = A[kt&1];
          if (kt+1 < 8) A[(kt+1)&1] = ldAf(s_actx, f, kt+1, lane);
          accg[0] = MFMA(a, b0, accg[0]);
          accg[1] = MFMA(a, b1f, accg[1]);
        }
      }
      __syncthreads();
      // value GEMM + epilogue: h += (t @ W2 + b2) * sigmoid(gate + bc)
      {
        f32x4 acc[2];
        acc[0]=(f32x4){0,0,0,0}; acc[1]=(f32x4){0,0,0,0};
        const short8v* Wv = Wpk8 + OFF_WSQ + (size_t)(j*3+1)*8192;
        float b2v[2] = { b2[(blk*2+j)*256 + n0*16 + rA], b2[(blk*2+j)*256 + (n0+1)*16 + rA] };
        float bcv[2] = { bc[(blk*2+j)*256 + n0*16 + rA], bc[(blk*2+j)*256 + (n0+1)*16 + rA] };
        short8v B[2][2], A[2];
        B[0][0] = Wv[(size_t)(0*16 + n0  )*64 + lane];
        B[0][1] = Wv[(size_t)(0*16 + n0+1)*64 + lane];
        B[1][0] = Wv[(size_t)(1*16 + n0  )*64 + lane];
        B[1][1] = Wv[(size_t)(1*16 + n0+1)*64 + lane];
        A[0] = ldAf(s_tb, f, 0, lane);
        #pragma unroll
        for (int kt=0; kt<8; ++kt){
          short8v b0 = B[kt&1][0], b1f = B[kt&1][1];
          if (kt+2 < 8){
            B[kt&1][0] = Wv[(size_t)((kt+2)*16 + n0  )*64 + lane];
            B[kt&1][1] = Wv[(size_t)((kt+2)*16 + n0+1)*64 + lane];
          }
          short8v a = A[kt&1];
          if (kt+1 < 8) A[(kt+1)&1] = ldAf(s_tb, f, kt+1, lane);
          acc[0] = MFMA(a, b0, acc[0]);
          acc[1] = MFMA(a, b1f, acc[1]);
        }
        bool last = (j == NRES-1);
        #pragma unroll
        for (int ni=0;ni<2;ni++){
          int col = (n0+ni)*16 + rA;
          #pragma unroll
          for (int r=0;r<4;r++){
            int row = f*16 + (lane>>4)*4 + r;
            float v = acc[ni][r] + b2v[ni];
            float g = accg[ni][r] + bcv[ni];
            float sg = 1.f/(1.f + expf(-g));
            float h = hreg[ni][r] + v*sg;
            hreg[ni][r] = h;
            stA(s_hr, row, col, last ? h : fmaxf(h, 0.f));  // G5 consumes PLAIN h
          }
        }
      }
      __syncthreads();
    }

    // ---- G5: p = h @ Wf + bf  (12 col-blocks; cb 0-5 own 2 each, both rfrags)
    if (cb < 6){
      f32x4 acc[2];
      acc[0] = (f32x4){0,0,0,0}; acc[1] = (f32x4){0,0,0,0};
      const short8v* Wp = Wpk8 + OFF_WF;
      int colA = n0*16 + rA, colB = (n0+1)*16 + rA;
      float bfv[2];
      bfv[0] = (colA < PDIM) ? bf_[blk*PDIM + colA] : 0.f;
      bfv[1] = (colB < PDIM) ? bf_[blk*PDIM + colB] : 0.f;
      short8v B[2][2], A[2];
      B[0][0] = Wp[(size_t)(0*12 + n0  )*64 + lane];
      B[0][1] = Wp[(size_t)(0*12 + n0+1)*64 + lane];
      B[1][0] = Wp[(size_t)(1*12 + n0  )*64 + lane];
      B[1][1] = Wp[(size_t)(1*12 + n0+1)*64 + lane];
      A[0] = ldAf(s_hr, f, 0, lane);
      #pragma unroll
      for (int kt=0; kt<8; ++kt){
        short8v b0 = B[kt&1][0], b1f = B[kt&1][1];
        if (kt+2 < 8){
          B[kt&1][0] = Wp[(size_t)((kt+2)*12 + n0  )*64 + lane];
          B[kt&1][1] = Wp[(size_t)((kt+2)*12 + n0+1)*64 + lane];
        }
        short8v a = A[kt&1];
        if (kt+1 < 8) A[(kt+1)&1] = ldAf(s_hr, f, kt+1, lane);
        acc[0] = MFMA(a, b0, acc[0]);
        acc[1] = MFMA(a, b1f, acc[1]);
      }
      #pragma unroll
      for (int ni=0;ni<2;ni++){
        int col = (n0+ni)*16 + rA;
        if (col < PDIM){
          #pragma unroll
          for (int r=0;r<4;r++){
            int row = f*16 + (lane>>4)*4 + r;
            s_pb[row][col] = acc[ni][r] + bfv[ni];
          }
        }
      }
    }
    __syncthreads();

    // ---- P8: conditional spline on odd dims + reinterleave; co-stage next blk
    if (tid < 256){
      int row = tid >> 3, k = tid & 7;
      float pr[23];
      #pragma unroll
      for (int jj=0;jj<23;jj++) pr[jj] = s_pb[row][k*23 + jj];
      float uw[8], uh[8], ud[7];
      #pragma unroll
      for (int b=0;b<8;b++){ uw[b] = pr[b]*0.0625f; uh[b] = pr[8+b]*0.0625f; }
      #pragma unroll
      for (int b=0;b<7;b++) ud[b] = pr[16+b];
      float o, nl;
      rqs_inv1(s_ztr[row][k], uw, uh, ud, &o, &nl);
      s_z[row][2*k]   = s_zid[row][k];
      s_z[row][2*k+1] = o;
      float t = nl;
      t += __shfl_xor(t,1); t += __shfl_xor(t,2); t += __shfl_xor(t,4);
      if (k == 0) s_ld[row] += t;
    } else if (blk > 0){
      stage_params(blk-1, tid - 512);
    }
  }
  __syncthreads();

  // ---- writeback
  if (tid < 512){
    int row = tid >> 4, c = tid & 15;
    zg[(r0+row)*16 + c] = s_z[row][c];
    if (tid < RB) logdet_g[r0+tid] = s_ld[tid];
  }
}

__global__ __launch_bounds__(64) void final_k(
  const float* __restrict__ ctx, const float* __restrict__ q0W,
  const float* __restrict__ q0b, const float* __restrict__ z,
  const float* __restrict__ logdet, float* __restrict__ out)
{
  int n = blockIdx.x*64 + threadIdx.x;
  if (n >= N_SAMP) return;
  float acc[2*LAT];
  #pragma unroll
  for (int m=0;m<2*LAT;m++) acc[m] = q0b[m];
  for (int k=0;k<CTXD;k+=4){
    float4 cv = *(const float4*)&ctx[n*CTXD + k];
    #pragma unroll
    for (int m=0;m<2*LAT;m++){
      acc[m] = fmaf(cv.x, q0W[(k+0)*2*LAT + m], acc[m]);
      acc[m] = fmaf(cv.y, q0W[(k+1)*2*LAT + m], acc[m]);
      acc[m] = fmaf(cv.z, q0W[(k+2)*2*LAT + m], acc[m]);
      acc[m] = fmaf(cv.w, q0W[(k+3)*2*LAT + m], acc[m]);
    }
  }
  float s = 0.f;
  #pragma unroll
  for (int dd=0;dd<LAT;dd++){
    float ls = acc[LAT+dd];
    float t = (z[n*LAT+dd] - acc[dd]) * expf(-ls);
    s += ls + 0.5f*t*t;
  }
  float logp = -14.703016531f - s;
  out[n] = -(logp + logdet[n]);
}

extern "C" void kernel_launch(void* const* d_in, const int* in_sizes, int n_in,
                              void* d_out, int out_size, void* d_ws, size_t ws_size,
                              hipStream_t stream)
{
  const float* x      = (const float*)d_in[0];
  const float* params = (const float*)d_in[1];
  const float* W_in   = (const float*)d_in[2];
  const float* b_in   = (const float*)d_in[3];
  const float* W1     = (const float*)d_in[4];
  const float* b1     = (const float*)d_in[5];
  const float* W2     = (const float*)d_in[6];
  const float* b2     = (const float*)d_in[7];
  const float* Wc     = (const float*)d_in[8];
  const float* bc     = (const float*)d_in[9];
  const float* Wf     = (const float*)d_in[10];
  const float* bf_    = (const float*)d_in[11];
  const float* un_w   = (const float*)d_in[12];
  const float* un_h   = (const float*)d_in[13];
  const float* un_d   = (const float*)d_in[14];
  const float* lu_lo  = (const float*)d_in[15];
  const float* lu_up  = (const float*)d_in[16];
  const float* lu_ud  = (const float*)d_in[17];
  const float* lu_b   = (const float*)d_in[18];
  const float* q0W    = (const float*)d_in[19];
  const float* q0b    = (const float*)d_in[20];
  const int*   perms  = (const int*)d_in[21];
  float* out = (float*)d_out;

  float* ws      = (float*)d_ws;
  float* z       = ws;                           // 131072 f
  float* logdet  = z + N_SAMP*LAT;               // 8192 f
  ushort_t* wpk  = (ushort_t*)(logdet + N_SAMP); // 4128768 us

  pack_w_k<<<dim3(2016), 256, 0, stream>>>(W_in, W1, W2, Wc, Wf, wpk);
  flow_k<<<dim3(N_SAMP/RB), 1024, 0, stream>>>(
      x, params, z, logdet, wpk,
      b_in, b1, b2, bc, bf_,
      un_w, un_h, un_d, lu_lo, lu_up, lu_ud, lu_b, perms);
  final_k<<<dim3(N_SAMP/64), 64, 0, stream>>>(params, q0W, q0b, z, logdet, out);
}

// Round 10
// 201.135 us; speedup vs baseline: 2.2180x; 1.7087x over previous
//
#include <hip/hip_runtime.h>
#include <math.h>

#define N_SAMP 8192
#define LAT 16
#define DID 8
#define DTR 8
#define KB 8
#define CTXD 256
#define HIDD 256
#define NRES 2
#define NBLK 8
#define PDIM 184
#define TAILF 3.0f
#define RB 32          // rows per WG; 1024 threads = 16 waves; 1 WG/CU

typedef unsigned short ushort_t;
typedef short short8v __attribute__((ext_vector_type(8)));
typedef float f32x4 __attribute__((ext_vector_type(4)));

// packed-weight sizes (elements)
#define WIN_PACK   73728   // 9 ksteps * 16 nblk * 512
#define WSQ_PACK   65536   // 8 * 16 * 512
#define WF_PACK    49152   // 8 * 12 * 512
#define BLK_PACK   516096  // WIN + 6*WSQ + WF
#define OFF_WSQ    9216    // in short8 units
#define OFF_WF     58368
#define Q0_OFF     (8*BLK_PACK)   // q0W pack: 8 kt * 2 nb * 512 = 8192 elements

__device__ __forceinline__ ushort_t f2bf(float f){
  unsigned u = __builtin_bit_cast(unsigned, f);
  unsigned r = (u + 0x7fffu + ((u>>16)&1u)) >> 16;
  return (ushort_t)r;
}
__device__ __forceinline__ float softplusf(float x){
  return (x > 20.0f) ? x : log1pf(expf(x));
}
__device__ __forceinline__ f32x4 MFMA(short8v a, short8v b, f32x4 c){
  return __builtin_amdgcn_mfma_f32_16x16x32_bf16(a, b, c, 0, 0, 0);
}

// ---- A-fragment-linear LDS tiles ----
__device__ __forceinline__ short8v ldAf(const ushort_t* tile, int rfrag, int kt, int lane){
  return *(const short8v*)(tile + (((kt*2 + rfrag)*64 + lane) << 3));
}
__device__ __forceinline__ void stA(ushort_t* tile, int row, int col, float v){
  int idx = ((((col>>5)*2 + (row>>4))*64) + (((col>>3)&3)<<4) + (row&15))*8 + (col&7);
  tile[idx] = f2bf(v);
}

// register-version inverse RQS (verified)
__device__ __forceinline__ void rqs_inv1(float x, const float* uw, const float* uh,
                                         const float* ud, float* outp, float* nladp)
{
  const float T = TAILF;
  bool inside = (x >= -T) && (x <= T);
  float cw[KB+1], wv[KB], ch[KB+1], hv[KB], dv[KB+1];
  {
    float m = uw[0];
    #pragma unroll
    for (int k=1;k<KB;k++) m = fmaxf(m, uw[k]);
    float e[KB]; float ssum = 0.f;
    #pragma unroll
    for (int k=0;k<KB;k++){ e[k] = expf(uw[k]-m); ssum += e[k]; }
    float inv = 1.f/ssum; float c = 0.f;
    cw[0] = -T;
    #pragma unroll
    for (int k=0;k<KB;k++){ c += 0.001f + (1.f-0.008f)*e[k]*inv; cw[k+1] = 2.f*T*c - T; }
    cw[KB] = T;
    #pragma unroll
    for (int k=0;k<KB;k++) wv[k] = cw[k+1]-cw[k];
  }
  {
    float m = uh[0];
    #pragma unroll
    for (int k=1;k<KB;k++) m = fmaxf(m, uh[k]);
    float e[KB]; float ssum = 0.f;
    #pragma unroll
    for (int k=0;k<KB;k++){ e[k] = expf(uh[k]-m); ssum += e[k]; }
    float inv = 1.f/ssum; float c = 0.f;
    ch[0] = -T;
    #pragma unroll
    for (int k=0;k<KB;k++){ c += 0.001f + (1.f-0.008f)*e[k]*inv; ch[k+1] = 2.f*T*c - T; }
    ch[KB] = T;
    #pragma unroll
    for (int k=0;k<KB;k++) hv[k] = ch[k+1]-ch[k];
  }
  dv[0] = 1.f; dv[KB] = 1.f;
  #pragma unroll
  for (int k=0;k<KB-1;k++) dv[k+1] = 0.001f + softplusf(ud[k]);

  float xc = fminf(fmaxf(x, -T), T);
  int idx = 0;
  #pragma unroll
  for (int k=1;k<KB;k++) idx += (xc >= ch[k]) ? 1 : 0;

  float icw=cw[0], iw=wv[0], ich=ch[0], ih=hv[0], d0=dv[0], d1=dv[1];
  #pragma unroll
  for (int k=1;k<KB;k++){
    bool sel = (idx==k);
    icw = sel?cw[k]:icw; iw = sel?wv[k]:iw; ich = sel?ch[k]:ich;
    ih = sel?hv[k]:ih; d0 = sel?dv[k]:d0; d1 = sel?dv[k+1]:d1;
  }
  float delta = ih/iw;
  float sq = d0 + d1 - 2.f*delta;
  float yv = xc - ich;
  float aa = yv*sq + ih*(delta-d0);
  float bb = ih*d0 - yv*sq;
  float cc = -delta*yv;
  float disc = fmaxf(bb*bb - 4.f*aa*cc, 0.f);
  float root = 2.f*cc / (-bb - sqrtf(disc));
  float o = root*iw + icw;
  float t1m = root*(1.f-root);
  float den = delta + sq*t1m;
  float num = delta*delta*(d1*root*root + 2.f*delta*t1m + d0*(1.f-root)*(1.f-root));
  float lad = logf(num) - 2.f*logf(den);
  *outp = inside ? o : x;
  *nladp = inside ? -lad : 0.f;
}

// LDS-knot apply (uncond spline)
__device__ __forceinline__ void rqs_apply_lds(float x, const float* cw, const float* ch,
                                              const float* dv, float* outp, float* nladp)
{
  const float T = TAILF;
  bool inside = (x >= -T) && (x <= T);
  float xc = fminf(fmaxf(x, -T), T);
  int idx = 0;
  #pragma unroll
  for (int k=1;k<KB;k++) idx += (xc >= ch[k]) ? 1 : 0;
  float icw = cw[idx], iw = cw[idx+1]-icw;
  float ich = ch[idx], ih = ch[idx+1]-ich;
  float d0 = dv[idx], d1 = dv[idx+1];
  float delta = ih/iw;
  float sq = d0 + d1 - 2.f*delta;
  float yv = xc - ich;
  float aa = yv*sq + ih*(delta-d0);
  float bb = ih*d0 - yv*sq;
  float cc = -delta*yv;
  float disc = fmaxf(bb*bb - 4.f*aa*cc, 0.f);
  float root = 2.f*cc / (-bb - sqrtf(disc));
  float o = root*iw + icw;
  float t1m = root*(1.f-root);
  float den = delta + sq*t1m;
  float num = delta*delta*(d1*root*root + 2.f*delta*t1m + d0*(1.f-root)*(1.f-root));
  float lad = logf(num) - 2.f*logf(den);
  *outp = inside ? o : x;
  *nladp = inside ? -lad : 0.f;
}

// pack all weights (+q0W) into B-fragment-linear bf16 layout
__global__ __launch_bounds__(256) void pack_w_k(
  const float* __restrict__ W_in, const float* __restrict__ W1, const float* __restrict__ W2,
  const float* __restrict__ Wc, const float* __restrict__ Wf, const float* __restrict__ q0W,
  ushort_t* __restrict__ wp)
{
  int t = blockIdx.x*256 + threadIdx.x;
  if (t >= 8*64512 + 1024) return;
  float vals[8];
  if (t >= 8*64512){
    // q0W pack: [256][32] -> 8 kt x 2 nb x 64 lanes x 8
    int r = t - 8*64512;
    int kt = r >> 7, nb = (r >> 6) & 1, lane = r & 63;
    ushort_t* dst = wp + (size_t)Q0_OFF + ((size_t)((kt*2 + nb)*64 + lane))*8;
    int col = nb*16 + (lane & 15);
    #pragma unroll
    for (int j=0;j<8;j++){
      int k = kt*32 + (lane>>4)*8 + j;
      vals[j] = q0W[k*32 + col];
    }
    #pragma unroll
    for (int j=0;j<8;j++) dst[j] = f2bf(vals[j]);
    return;
  }
  int blk = t / 64512;
  int r = t % 64512;
  ushort_t* dst = wp + (size_t)blk*BLK_PACK;
  if (r < 9216){
    int kt = r/1024, n = (r/64)%16, lane = r%64;
    const float* w = W_in + (size_t)blk*264*256;
    int col = n*16 + (lane&15);
    #pragma unroll
    for (int j=0;j<8;j++){
      int k = kt*32 + (lane>>4)*8 + j;
      vals[j] = (k < 32) ? ((k < 8) ? w[k*256+col] : 0.f) : w[(k-24)*256+col];
    }
    dst += ((size_t)(kt*16+n)*64 + lane)*8;
  } else if ((r -= 9216) < 49152){
    int m = r/8192, rr = r%8192;
    int kt = rr/1024, n = (rr/64)%16, lane = rr%64;
    int j2 = m/3, which = m%3;
    const float* w = (which==0 ? W1 : which==1 ? W2 : Wc) + (size_t)(blk*2+j2)*256*256;
    int col = n*16 + (lane&15);
    #pragma unroll
    for (int j=0;j<8;j++){
      int k = kt*32 + (lane>>4)*8 + j;
      vals[j] = w[k*256+col];
    }
    dst += WIN_PACK + (size_t)m*WSQ_PACK + ((size_t)(kt*16+n)*64+lane)*8;
  } else {
    r -= 49152;
    int kt = r/768, n = (r/64)%12, lane = r%64;
    const float* w = Wf + (size_t)blk*256*184;
    int col = n*16 + (lane&15);
    #pragma unroll
    for (int j=0;j<8;j++){
      int k = kt*32 + (lane>>4)*8 + j;
      vals[j] = (col < 184) ? w[k*184+col] : 0.f;
    }
    dst += (size_t)OFF_WF*8 + ((size_t)(kt*12+n)*64+lane)*8;
  }
  #pragma unroll
  for (int j=0;j<8;j++) dst[j] = f2bf(vals[j]);
}

// ---- ONE fused kernel: init + all 8 flow blocks + base NLL; 1024 thr, 1 WG/CU ----
__global__ __launch_bounds__(1024,4) void flow_k(
  const float* __restrict__ x, const float* __restrict__ params,
  float* __restrict__ out,
  const ushort_t* __restrict__ wpack,
  const float* __restrict__ b_in, const float* __restrict__ b1, const float* __restrict__ b2,
  const float* __restrict__ bc, const float* __restrict__ bf_,
  const float* __restrict__ un_w, const float* __restrict__ un_h, const float* __restrict__ un_d,
  const float* __restrict__ lu_lo, const float* __restrict__ lu_up,
  const float* __restrict__ lu_ud, const float* __restrict__ lu_b,
  const float* __restrict__ q0b, const int* __restrict__ perms)
{
  __shared__ ushort_t s_actx[8192];   // ctx bf16, A-linear, resident whole kernel (16KB)
  __shared__ ushort_t s_hr[8192];     // relu(h)/h bf16, A-linear (16KB)
  __shared__ ushort_t s_tb[8192];     // relu(t1) bf16, A-linear (16KB)
  __shared__ ushort_t s_azid[1024];   // G1 kt0 A tile (zid | zeros), A-linear (2KB)
  __shared__ float s_z[RB][16], s_y[RB][16];
  __shared__ float s_zid[RB][8], s_ztr[RB][8];
  __shared__ float s_pb[RB][193];     // spline params / final enc (pad 193)
  __shared__ float s_ld[RB];
  __shared__ float s_ucw[8][9], s_uch[8][9], s_ud8[8][9];
  __shared__ float s_lulo[120], s_luup[120], s_dg[16], s_slog[16], s_lub[16];
  __shared__ int   s_perm[16];

  const int tid = threadIdx.x;
  const int r0 = blockIdx.x * RB;
  const int wid = tid >> 6, lane = tid & 63;
  const int rA = lane & 15;

  auto stage_params = [&](int blk, int t2){
    if (t2 >= 0 && t2 < 120){
      s_lulo[t2] = lu_lo[blk*120 + t2];
      s_luup[t2] = lu_up[blk*120 + t2];
    } else if (t2 >= 128 && t2 < 144){
      int c = t2 - 128;
      s_perm[c] = perms[blk*16 + c];
      float dg = softplusf(lu_ud[blk*16 + c]) + 0.001f;
      s_dg[c] = dg; s_slog[c] = logf(dg);
      s_lub[c] = lu_b[blk*16 + c];
    } else if (t2 >= 192 && t2 < 200){
      int k8 = t2 - 192;
      const float* uwp = un_w + blk*64 + k8*8;
      const float* uhp = un_h + blk*64 + k8*8;
      const float* udp = un_d + blk*56 + k8*7;
      float m = uwp[0];
      #pragma unroll
      for (int k=1;k<8;k++) m = fmaxf(m, uwp[k]);
      float e[8], s = 0.f;
      #pragma unroll
      for (int k=0;k<8;k++){ e[k]=expf(uwp[k]-m); s+=e[k]; }
      float inv = 1.f/s, c = 0.f;
      s_ucw[k8][0] = -TAILF;
      #pragma unroll
      for (int k=0;k<8;k++){ c += 0.001f + (1.f-0.008f)*e[k]*inv; s_ucw[k8][k+1] = 2.f*TAILF*c - TAILF; }
      s_ucw[k8][8] = TAILF;
      m = uhp[0];
      #pragma unroll
      for (int k=1;k<8;k++) m = fmaxf(m, uhp[k]);
      s = 0.f;
      #pragma unroll
      for (int k=0;k<8;k++){ e[k]=expf(uhp[k]-m); s+=e[k]; }
      inv = 1.f/s; c = 0.f;
      s_uch[k8][0] = -TAILF;
      #pragma unroll
      for (int k=0;k<8;k++){ c += 0.001f + (1.f-0.008f)*e[k]*inv; s_uch[k8][k+1] = 2.f*TAILF*c - TAILF; }
      s_uch[k8][8] = TAILF;
      s_ud8[k8][0] = 1.f; s_ud8[k8][8] = 1.f;
      #pragma unroll
      for (int k=0;k<7;k++) s_ud8[k8][k+1] = 0.001f + softplusf(udp[k]);
    }
  };

  // ---- P0 (once): stage x, ctx(f32->bf16 A-linear), azid pad, logdet, blk7 params
  if (tid < 512){
    int row = tid >> 4, c = tid & 15;
    s_z[row][c] = x[(r0+row)*16 + c];
    const float* src = params + (size_t)(r0+row)*256 + c*16;
    float f[16];
    #pragma unroll
    for (int q=0;q<4;q++){
      float4 v = *(const float4*)(src + q*4);
      f[q*4]=v.x; f[q*4+1]=v.y; f[q*4+2]=v.z; f[q*4+3]=v.w;
    }
    short8v v0, v1;
    #pragma unroll
    for (int j=0;j<8;j++){ v0[j]=(short)f2bf(f[j]); v1[j]=(short)f2bf(f[8+j]); }
    int b = ((((c>>1)*2 + (row>>4))*64) + ((c&1)*2)*16 + (row&15))*8;
    *(short8v*)(s_actx + b)       = v0;
    *(short8v*)(s_actx + b + 128) = v1;
    if (tid < RB) s_ld[tid] = 0.f;
  } else {
    stage_params(NBLK-1, tid - 512);
  }
  // zero azid octs 1..3
  for (int i = tid; i < 96; i += 1024){
    int rf = i/48, rem = i%48, oct = 1 + rem/16, r = rem%16;
    short8v zv = (short8v){0,0,0,0,0,0,0,0};
    *(short8v*)(s_azid + ((rf*64 + oct*16 + r)<<3)) = zv;
  }

  float hreg[2][4];

  for (int blk = NBLK-1; blk >= 0; --blk){
    __syncthreads();

    // ---- P1: U apply (permuted input)
    if (tid < 512){
      int row = tid >> 4, c = tid & 15;
      float zp[16];
      #pragma unroll
      for (int cc=0;cc<16;cc++) zp[cc] = s_z[row][s_perm[cc]];
      float acc = s_dg[c]*zp[c];
      #pragma unroll
      for (int cc=0;cc<16;cc++)
        if (cc > c) acc += s_luup[c*15 - (c*(c-1))/2 + (cc-c-1)] * zp[cc];
      s_y[row][c] = acc;
    }
    __syncthreads();

    // ---- P2: L apply + bias (overwrite s_z with w)
    if (tid < 512){
      int row = tid >> 4, c = tid & 15;
      float yp[16];
      #pragma unroll
      for (int cc=0;cc<16;cc++) yp[cc] = s_y[row][cc];
      float acc = yp[c] + s_lub[c];
      #pragma unroll
      for (int cc=0;cc<16;cc++)
        if (cc < c) acc += s_lulo[(c*(c-1))/2 + cc] * yp[cc];
      s_z[row][c] = acc;
    }
    __syncthreads();

    // ---- P4: uncond spline on even dims
    if (tid < 256){
      int row = tid >> 3, k = tid & 7;
      float o, nl;
      rqs_apply_lds(s_z[row][2*k], s_ucw[k], s_uch[k], s_ud8[k], &o, &nl);
      s_zid[row][k] = o;
      s_ztr[row][k] = s_z[row][2*k+1];
      s_azid[(((row>>4)*64) + (row&15))*8 + k] = f2bf(o);   // oct0, e=k
      float t = nl;
      t += __shfl_xor(t,1); t += __shfl_xor(t,2); t += __shfl_xor(t,4);
      if (k == 0){
        float sl = 0.f;
        #pragma unroll
        for (int c=0;c<16;c++) sl += s_slog[c];
        s_ld[row] += sl + t;
      }
    }
    __syncthreads();

    const short8v* Wpk8 = (const short8v*)(wpack + (size_t)blk*BLK_PACK);

    // ---- G1: h = [zid|ctx] @ W_in + b_in  (KT=9; A from LDS; B depth-4 roll)
    {
      f32x4 acc[2];
      acc[0] = (f32x4){0,0,0,0}; acc[1] = (f32x4){0,0,0,0};
      const short8v* Wp = Wpk8;
      float bvv = b_in[blk*256 + wid*16 + rA];
      short8v az0 = *(const short8v*)(s_azid + (lane<<3));
      short8v az1 = *(const short8v*)(s_azid + ((64 + lane)<<3));
      short8v B[4];
      #pragma unroll
      for (int s=0;s<4;s++) B[s] = Wp[(size_t)(s*16 + wid)*64 + lane];
      short8v An0 = az0, An1 = az1, Ac0, Ac1;
      Ac0 = ldAf(s_actx, 0, 0, lane); Ac1 = ldAf(s_actx, 1, 0, lane);
      #pragma unroll
      for (int kt=0; kt<9; ++kt){
        short8v b = B[kt&3];
        if (kt+4 < 9) B[kt&3] = Wp[(size_t)((kt+4)*16 + wid)*64 + lane];
        short8v a0 = (kt==0) ? az0 : Ac0;
        short8v a1 = (kt==0) ? az1 : Ac1;
        if (kt>0 && kt+1 < 9){
          Ac0 = ldAf(s_actx, 0, kt, lane);
          Ac1 = ldAf(s_actx, 1, kt, lane);
        }
        acc[0] = MFMA(a0, b, acc[0]);
        acc[1] = MFMA(a1, b, acc[1]);
      }
      int col = wid*16 + rA;
      #pragma unroll
      for (int f=0;f<2;f++)
        #pragma unroll
        for (int r=0;r<4;r++){
          int row = f*16 + (lane>>4)*4 + r;
          float h = acc[f][r] + bvv;
          hreg[f][r] = h;
          stA(s_hr, row, col, fmaxf(h, 0.f));
        }
    }
    __syncthreads();

    // ---- residual blocks
    #pragma unroll
    for (int j=0;j<NRES;j++){
      // S1: t = relu(relu(h) @ W1 + b1)   (A depth-2 from s_hr; B depth-4)
      {
        f32x4 acc[2];
        acc[0] = (f32x4){0,0,0,0}; acc[1] = (f32x4){0,0,0,0};
        const short8v* Wp = Wpk8 + OFF_WSQ + (size_t)(j*3+0)*8192;
        float bvv = b1[(blk*2+j)*256 + wid*16 + rA];
        short8v B[4], A0[2][2];
        #pragma unroll
        for (int s=0;s<4;s++) B[s] = Wp[(size_t)(s*16 + wid)*64 + lane];
        #pragma unroll
        for (int q=0;q<2;q++){ A0[0][q] = ldAf(s_hr, 0, q, lane); A0[1][q] = ldAf(s_hr, 1, q, lane); }
        #pragma unroll
        for (int kt=0; kt<8; ++kt){
          short8v b = B[kt&3];
          if (kt+4 < 8) B[kt&3] = Wp[(size_t)((kt+4)*16 + wid)*64 + lane];
          short8v a0 = A0[0][kt&1], a1 = A0[1][kt&1];
          if (kt+2 < 8){
            A0[0][kt&1] = ldAf(s_hr, 0, kt+2, lane);
            A0[1][kt&1] = ldAf(s_hr, 1, kt+2, lane);
          }
          acc[0] = MFMA(a0, b, acc[0]);
          acc[1] = MFMA(a1, b, acc[1]);
        }
        int col = wid*16 + rA;
        #pragma unroll
        for (int f=0;f<2;f++)
          #pragma unroll
          for (int r=0;r<4;r++){
            int row = f*16 + (lane>>4)*4 + r;
            stA(s_tb, row, col, fmaxf(acc[f][r] + bvv, 0.f));
          }
      }
      __syncthreads();
      // S2: h += (t @ W2 + b2) * sigmoid(ctx @ Wc + bc)
      {
        f32x4 acc[2], accg[2];
        acc[0]=(f32x4){0,0,0,0}; acc[1]=(f32x4){0,0,0,0};
        accg[0]=(f32x4){0,0,0,0}; accg[1]=(f32x4){0,0,0,0};
        float b2v = b2[(blk*2+j)*256 + wid*16 + rA];
        float bcv = bc[(blk*2+j)*256 + wid*16 + rA];
        // gate: accg = ctx @ Wc   (A depth-2 from s_actx; B depth-4)
        {
          const short8v* Wg = Wpk8 + OFF_WSQ + (size_t)(j*3+2)*8192;
          short8v B[4], A0[2][2];
          #pragma unroll
          for (int s=0;s<4;s++) B[s] = Wg[(size_t)(s*16 + wid)*64 + lane];
          #pragma unroll
          for (int q=0;q<2;q++){ A0[0][q] = ldAf(s_actx, 0, q, lane); A0[1][q] = ldAf(s_actx, 1, q, lane); }
          #pragma unroll
          for (int kt=0; kt<8; ++kt){
            short8v b = B[kt&3];
            if (kt+4 < 8) B[kt&3] = Wg[(size_t)((kt+4)*16 + wid)*64 + lane];
            short8v a0 = A0[0][kt&1], a1 = A0[1][kt&1];
            if (kt+2 < 8){
              A0[0][kt&1] = ldAf(s_actx, 0, kt+2, lane);
              A0[1][kt&1] = ldAf(s_actx, 1, kt+2, lane);
            }
            accg[0] = MFMA(a0, b, accg[0]);
            accg[1] = MFMA(a1, b, accg[1]);
          }
        }
        // value: acc = t @ W2   (A depth-2 from s_tb; B depth-4)
        {
          const short8v* Wv = Wpk8 + OFF_WSQ + (size_t)(j*3+1)*8192;
          short8v B[4], A0[2][2];
          #pragma unroll
          for (int s=0;s<4;s++) B[s] = Wv[(size_t)(s*16 + wid)*64 + lane];
          #pragma unroll
          for (int q=0;q<2;q++){ A0[0][q] = ldAf(s_tb, 0, q, lane); A0[1][q] = ldAf(s_tb, 1, q, lane); }
          #pragma unroll
          for (int kt=0; kt<8; ++kt){
            short8v b = B[kt&3];
            if (kt+4 < 8) B[kt&3] = Wv[(size_t)((kt+4)*16 + wid)*64 + lane];
            short8v a0 = A0[0][kt&1], a1 = A0[1][kt&1];
            if (kt+2 < 8){
              A0[0][kt&1] = ldAf(s_tb, 0, kt+2, lane);
              A0[1][kt&1] = ldAf(s_tb, 1, kt+2, lane);
            }
            acc[0] = MFMA(a0, b, acc[0]);
            acc[1] = MFMA(a1, b, acc[1]);
          }
        }
        bool last = (j == NRES-1);
        int col = wid*16 + rA;
        #pragma unroll
        for (int f=0;f<2;f++)
          #pragma unroll
          for (int r=0;r<4;r++){
            int row = f*16 + (lane>>4)*4 + r;
            float v = acc[f][r] + b2v;
            float g = accg[f][r] + bcv;
            float sg = 1.f/(1.f + expf(-g));
            float h = hreg[f][r] + v*sg;
            hreg[f][r] = h;
            stA(s_hr, row, col, last ? h : fmaxf(h, 0.f));  // G5 consumes PLAIN h
          }
      }
      __syncthreads();
    }

    // ---- G5: p = h @ Wf + bf  (12 col-blocks; waves 0-11; A depth-2; B depth-4)
    if (wid < 12){
      f32x4 acc[2];
      acc[0] = (f32x4){0,0,0,0}; acc[1] = (f32x4){0,0,0,0};
      const short8v* Wp = Wpk8 + OFF_WF;
      int col = wid*16 + rA;
      float bfv = (col < PDIM) ? bf_[blk*PDIM + col] : 0.f;
      short8v B[4], A0[2][2];
      #pragma unroll
      for (int s=0;s<4;s++) B[s] = Wp[(size_t)(s*12 + wid)*64 + lane];
      #pragma unroll
      for (int q=0;q<2;q++){ A0[0][q] = ldAf(s_hr, 0, q, lane); A0[1][q] = ldAf(s_hr, 1, q, lane); }
      #pragma unroll
      for (int kt=0; kt<8; ++kt){
        short8v b = B[kt&3];
        if (kt+4 < 8) B[kt&3] = Wp[(size_t)((kt+4)*12 + wid)*64 + lane];
        short8v a0 = A0[0][kt&1], a1 = A0[1][kt&1];
        if (kt+2 < 8){
          A0[0][kt&1] = ldAf(s_hr, 0, kt+2, lane);
          A0[1][kt&1] = ldAf(s_hr, 1, kt+2, lane);
        }
        acc[0] = MFMA(a0, b, acc[0]);
        acc[1] = MFMA(a1, b, acc[1]);
      }
      if (col < PDIM){
        #pragma unroll
        for (int f=0;f<2;f++)
          #pragma unroll
          for (int r=0;r<4;r++){
            int row = f*16 + (lane>>4)*4 + r;
            s_pb[row][col] = acc[f][r] + bfv;
          }
      }
    }
    __syncthreads();

    // ---- P8: conditional spline on odd dims + reinterleave; co-stage next blk
    if (tid < 256){
      int row = tid >> 3, k = tid & 7;
      float pr[23];
      #pragma unroll
      for (int jj=0;jj<23;jj++) pr[jj] = s_pb[row][k*23 + jj];
      float uw[8], uh[8], ud[7];
      #pragma unroll
      for (int b=0;b<8;b++){ uw[b] = pr[b]*0.0625f; uh[b] = pr[8+b]*0.0625f; }
      #pragma unroll
      for (int b=0;b<7;b++) ud[b] = pr[16+b];
      float o, nl;
      rqs_inv1(s_ztr[row][k], uw, uh, ud, &o, &nl);
      s_z[row][2*k]   = s_zid[row][k];
      s_z[row][2*k+1] = o;
      float t = nl;
      t += __shfl_xor(t,1); t += __shfl_xor(t,2); t += __shfl_xor(t,4);
      if (k == 0) s_ld[row] += t;
    } else if (blk > 0){
      stage_params(blk-1, tid - 512);
    }
  }
  __syncthreads();

  // ---- G6: enc = ctx @ q0W + q0b  (32 cols; waves 0-3: f=wid>>1, nb=wid&1)
  if (wid < 4){
    const int f = wid >> 1, nb = wid & 1;
    f32x4 acc = (f32x4){0,0,0,0};
    const short8v* Qp = (const short8v*)(wpack + (size_t)Q0_OFF);
    short8v B[4];
    #pragma unroll
    for (int s=0;s<4;s++) B[s] = Qp[(size_t)(s*2 + nb)*64 + lane];
    #pragma unroll
    for (int kt=0; kt<8; ++kt){
      short8v b = B[kt&3];
      if (kt+4 < 8) B[kt&3] = Qp[(size_t)((kt+4)*2 + nb)*64 + lane];
      acc = MFMA(ldAf(s_actx, f, kt, lane), b, acc);
    }
    int col = nb*16 + rA;
    float qb = q0b[col];
    #pragma unroll
    for (int r=0;r<4;r++){
      int row = f*16 + (lane>>4)*4 + r;
      s_pb[row][col] = acc[r] + qb;
    }
  }
  __syncthreads();

  // ---- P9: NLL per sample; 512 threads (row, d)
  if (tid < 512){
    int row = tid >> 4, d = tid & 15;
    float mean = s_pb[row][d];
    float ls   = s_pb[row][16 + d];
    float t = (s_z[row][d] - mean) * expf(-ls);
    float term = ls + 0.5f*t*t;
    term += __shfl_xor(term, 1);
    term += __shfl_xor(term, 2);
    term += __shfl_xor(term, 4);
    term += __shfl_xor(term, 8);
    if (d == 0)
      out[r0 + row] = 14.703016531f + term - s_ld[row];
  }
}

extern "C" void kernel_launch(void* const* d_in, const int* in_sizes, int n_in,
                              void* d_out, int out_size, void* d_ws, size_t ws_size,
                              hipStream_t stream)
{
  const float* x      = (const float*)d_in[0];
  const float* params = (const float*)d_in[1];
  const float* W_in   = (const float*)d_in[2];
  const float* b_in   = (const float*)d_in[3];
  const float* W1     = (const float*)d_in[4];
  const float* b1     = (const float*)d_in[5];
  const float* W2     = (const float*)d_in[6];
  const float* b2     = (const float*)d_in[7];
  const float* Wc     = (const float*)d_in[8];
  const float* bc     = (const float*)d_in[9];
  const float* Wf     = (const float*)d_in[10];
  const float* bf_    = (const float*)d_in[11];
  const float* un_w   = (const float*)d_in[12];
  const float* un_h   = (const float*)d_in[13];
  const float* un_d   = (const float*)d_in[14];
  const float* lu_lo  = (const float*)d_in[15];
  const float* lu_up  = (const float*)d_in[16];
  const float* lu_ud  = (const float*)d_in[17];
  const float* lu_b   = (const float*)d_in[18];
  const float* q0W    = (const float*)d_in[19];
  const float* q0b    = (const float*)d_in[20];
  const int*   perms  = (const int*)d_in[21];
  float* out = (float*)d_out;

  ushort_t* wpk = (ushort_t*)d_ws;   // 8*BLK_PACK + 8192 elements

  pack_w_k<<<dim3(2020), 256, 0, stream>>>(W_in, W1, W2, Wc, Wf, q0W, wpk);
  flow_k<<<dim3(N_SAMP/RB), 1024, 0, stream>>>(
      x, params, out, wpk,
      b_in, b1, b2, bc, bf_,
      un_w, un_h, un_d, lu_lo, lu_up, lu_ud, lu_b, q0b, perms);
}